// Round 5
// baseline (56.794 us; speedup 1.0000x reference)
//
#include <hip/hip_runtime.h>
#include <hip/hip_bf16.h>
#include <math.h>

#define S_SAMPLED 1000
#define SPAD      1024
#define DIM       512
#define BATCH     8192

#define BM 64
#define BN 256
#define BKT 32                   // K per tile (64 bytes)
#define KTILES (DIM / BKT)       // 16
#define NCHUNK 4
#define GEMM_BLOCKS 512          // (BATCH/BM) * NCHUNK
#define TRUE_BLOCKS 256          // BATCH / 32
#define TOTAL_BLOCKS (GEMM_BLOCKS + TRUE_BLOCKS)
#define M0C 20.0f                // fixed softmax max bound (logits <= ~10)

typedef __attribute__((ext_vector_type(8))) short short8_t;  // 8 bf16
typedef __attribute__((ext_vector_type(4))) float f32x4_t;

__device__ __forceinline__ float neg_log_expected(int c) {
    const float log_vp1 = 11.5129354649f;   // log(100001)
    float p = log1pf(1.0f / (float)(c + 1)) / log_vp1;
    float E = -expm1f((float)S_SAMPLED * log1pf(-p));
    return -logf(E);
}

__device__ __forceinline__ unsigned short f2bf(float x) {
    __hip_bfloat16 h = __float2bfloat16(x);
    union { __hip_bfloat16 h; unsigned short u; } cv; cv.h = h; return cv.u;
}

__device__ __forceinline__ float b2f(short u) {
    union { float f; unsigned u; } c;
    c.u = ((unsigned)(unsigned short)u) << 16;
    return c.f;
}

__device__ __forceinline__ void load_lds16(const void* g, void* l) {
    __builtin_amdgcn_global_load_lds(
        (const __attribute__((address_space(1))) void*)g,
        (__attribute__((address_space(3))) void*)l, 16, 0, 0);
}

// involution on byte addr for 64-B rows: bits 4-5 ^= row&3
__device__ __forceinline__ int swz32(int lin) { return lin ^ (((lin >> 6) & 3) << 4); }

// ------------- kernel 0: prep ------------------------------------------------
// blocks 0..511   : gather+cast W[sampled] -> Wg bf16 (2 rows/blk) + adj
// blocks 512..2559: cast y_pred f32 -> bf16 (2048 elems/blk)
__global__ __launch_bounds__(256) void prep_kernel(
    const float* __restrict__ y_pred, const float* __restrict__ W,
    const float* __restrict__ b, const int* __restrict__ sampled,
    unsigned short* __restrict__ Wg, float* __restrict__ adj,
    unsigned short* __restrict__ ypredB, int* __restrict__ counter)
{
    int bid = blockIdx.x;
    if (bid == 0 && threadIdx.x == 0) *counter = 0;
    if (bid < 512) {
        int row = bid * 2 + (threadIdx.x >> 7);   // 0..1023
        int t   = threadIdx.x & 127;              // 128 threads * 4 elems
        if (t == 0) {
            if (row < S_SAMPLED) {
                int c = sampled[row];
                adj[row] = b[c] + neg_log_expected(c);
            } else adj[row] = -1e30f;
        }
        unsigned short* dst = Wg + (size_t)row * DIM + t * 4;
        if (row < S_SAMPLED) {
            float4 f = *(const float4*)(W + (size_t)sampled[row] * DIM + t * 4);
            ushort4 o;
            o.x = f2bf(f.x); o.y = f2bf(f.y); o.z = f2bf(f.z); o.w = f2bf(f.w);
            *(ushort4*)dst = o;
        } else {
            *(ushort4*)dst = make_ushort4(0, 0, 0, 0);
        }
    } else {
        int i = (bid - 512) * 2048 + threadIdx.x * 8;
        float4 f0 = *(const float4*)(y_pred + i);
        float4 f1 = *(const float4*)(y_pred + i + 4);
        uint4 o;
        o.x = (unsigned)f2bf(f0.x) | ((unsigned)f2bf(f0.y) << 16);
        o.y = (unsigned)f2bf(f0.z) | ((unsigned)f2bf(f0.w) << 16);
        o.z = (unsigned)f2bf(f1.x) | ((unsigned)f2bf(f1.y) << 16);
        o.w = (unsigned)f2bf(f1.z) | ((unsigned)f2bf(f1.w) << 16);
        *(uint4*)(ypredB + i) = o;
    }
}

// ------------- kernel 1: fused GEMM + true-logits + finalize ----------------
// blocks 0..511  : MFMA GEMM, BM=64 x BN=256, psum of exp(logit-M0) per chunk
// blocks 512..767: true logits (bf16 y_pred . f32 W[label]), 32 rows/blk
// last block     : merges psum + true_v -> mean loss (atomic counter)
__global__ __launch_bounds__(256, 3) void gemm_fused_kernel(
    const unsigned short* __restrict__ Abf,   // y_pred bf16 [BATCH][DIM]
    const unsigned short* __restrict__ Wg,    // gathered W bf16 [SPAD][DIM]
    const int*   __restrict__ sampled,
    const float* __restrict__ adj,
    const int*   __restrict__ y_true,
    const float* __restrict__ W,              // f32, for true-logit gather
    const float* __restrict__ b,
    float* __restrict__ true_v,               // [BATCH]
    float* __restrict__ psum,                 // [BATCH][NCHUNK]
    int*   __restrict__ counter,
    float* __restrict__ out)
{
    // LDS: As dbuf 2x4KB | Bs dbuf 2x16KB | reds [2][64] f32
    __shared__ __align__(16) char smem[41472];
    __shared__ int s_last;
    char* As0 = smem;
    char* As1 = smem + 4096;
    char* Bs0 = smem + 8192;
    char* Bs1 = smem + 24576;
    float* reds = (float*)(smem + 40960);

    const int tid = threadIdx.x;

    if (blockIdx.x < GEMM_BLOCKS) {
        // XCD-aware remap: all 4 n-chunks of an m-stripe on one XCD
        int wg = blockIdx.x;
        int sw = (wg & 7) * 64 + (wg >> 3);       // bijective, 512 blocks
        const int m0    = (sw >> 2) * BM;
        const int chunk = sw & 3;
        const int n0    = chunk * BN;

        const int lane = tid & 63;
        const int wid  = tid >> 6;
        const int wr   = wid >> 1;
        const int wc   = wid & 1;
        const int g    = lane >> 4;
        const int lcol = lane & 15;

        const char* AB = (const char*)Abf;
        const char* WB = (const char*)Wg;

        // staging: linear LDS dest (tid*16), source pre-inverse-swizzled
        int d0   = tid * 16;
        int arow = d0 >> 6;
        int a_src = (m0 + arow) * (DIM * 2) + ((d0 & 63) ^ ((arow & 3) << 4));
        int b_src[4];
#pragma unroll
        for (int it = 0; it < 4; ++it) {
            int d = it * 4096 + tid * 16;
            int col = d >> 6;
            b_src[it] = (n0 + col) * (DIM * 2) + ((d & 63) ^ ((col & 3) << 4));
        }

        int a_roff[2], b_roff[8];
#pragma unroll
        for (int mi = 0; mi < 2; ++mi)
            a_roff[mi] = swz32((wr * 32 + mi * 16 + lcol) * 64 + g * 16);
#pragma unroll
        for (int nj = 0; nj < 8; ++nj)
            b_roff[nj] = swz32((wc * 128 + nj * 16 + lcol) * 64 + g * 16);

        f32x4_t acc[2][8] = {};

#define STAGE(AsP, BsP, kt) do {                                       \
            int kb_ = (kt) * (BKT * 2);                                \
            load_lds16(AB + a_src + kb_, (AsP) + tid * 16);            \
            load_lds16(WB + b_src[0] + kb_, (BsP) + tid * 16);         \
            load_lds16(WB + b_src[1] + kb_, (BsP) + 4096 + tid * 16);  \
            load_lds16(WB + b_src[2] + kb_, (BsP) + 8192 + tid * 16);  \
            load_lds16(WB + b_src[3] + kb_, (BsP) + 12288 + tid * 16); \
        } while (0)

#define COMPUTE(AsP, BsP) do {                                                        \
            short8_t a0 = *(const short8_t*)((AsP) + a_roff[0]);                      \
            short8_t a1 = *(const short8_t*)((AsP) + a_roff[1]);                      \
            _Pragma("unroll")                                                         \
            for (int nj = 0; nj < 8; ++nj) {                                          \
                short8_t bv = *(const short8_t*)((BsP) + b_roff[nj]);                 \
                acc[0][nj] = __builtin_amdgcn_mfma_f32_16x16x32_bf16(a0, bv, acc[0][nj], 0, 0, 0); \
                acc[1][nj] = __builtin_amdgcn_mfma_f32_16x16x32_bf16(a1, bv, acc[1][nj], 0, 0, 0); \
            }                                                                         \
        } while (0)

        __builtin_amdgcn_sched_barrier(0);
        STAGE(As0, Bs0, 0);
        STAGE(As1, Bs1, 1);
#pragma unroll
        for (int t = 0; t < KTILES; ++t) {
            if (t < KTILES - 1) asm volatile("s_waitcnt vmcnt(5)" ::: "memory");
            else                asm volatile("s_waitcnt vmcnt(0)" ::: "memory");
            __builtin_amdgcn_s_barrier();
            __builtin_amdgcn_sched_barrier(0);
            const char* AsP = (t & 1) ? As1 : As0;
            const char* BsP = (t & 1) ? Bs1 : Bs0;
            __builtin_amdgcn_s_setprio(1);
            COMPUTE(AsP, BsP);
            __builtin_amdgcn_s_setprio(0);
            __builtin_amdgcn_sched_barrier(0);
            __builtin_amdgcn_s_barrier();
            if (t + 2 < KTILES) STAGE((t & 1) ? As1 : As0, (t & 1) ? Bs1 : Bs0, t + 2);
        }
        __builtin_amdgcn_sched_barrier(0);

        // ---- epilogue: adj + hit mask, fixed-max partial sum of exp ----
        // C layout: col = lane&15, row = (lane>>4)*4 + r
        int labs[2][4];
        float srow[2][4];
#pragma unroll
        for (int mi = 0; mi < 2; ++mi)
#pragma unroll
            for (int r = 0; r < 4; ++r) {
                labs[mi][r] = y_true[m0 + wr * 32 + mi * 16 + g * 4 + r];
                srow[mi][r] = 0.f;
            }

        float ajv[8]; int scv[8];
#pragma unroll
        for (int nj = 0; nj < 8; ++nj) {
            int cg = n0 + wc * 128 + nj * 16 + lcol;
            ajv[nj] = adj[cg];
            scv[nj] = (cg < S_SAMPLED) ? sampled[cg] : -2147483647;
        }

#pragma unroll
        for (int mi = 0; mi < 2; ++mi)
#pragma unroll
            for (int nj = 0; nj < 8; ++nj) {
#pragma unroll
                for (int r = 0; r < 4; ++r) {
                    float x = acc[mi][nj][r] + ajv[nj];
                    if (scv[nj] == labs[mi][r]) x -= 1e9f;
                    srow[mi][r] += expf(x - M0C);
                }
            }

#pragma unroll
        for (int s = 1; s < 16; s <<= 1)
#pragma unroll
            for (int mi = 0; mi < 2; ++mi)
#pragma unroll
                for (int r = 0; r < 4; ++r)
                    srow[mi][r] += __shfl_xor(srow[mi][r], s);
        if (lcol == 0) {
#pragma unroll
            for (int mi = 0; mi < 2; ++mi)
#pragma unroll
                for (int r = 0; r < 4; ++r)
                    reds[wc * 64 + wr * 32 + mi * 16 + g * 4 + r] = srow[mi][r];
        }
        __syncthreads();
        if (tid < BM)
            psum[(size_t)(m0 + tid) * NCHUNK + chunk] = reds[tid] + reds[64 + tid];
#undef STAGE
#undef COMPUTE
    } else {
        // ---- true-logit blocks: 32 rows each, one wave per row-iteration ----
        int tb   = blockIdx.x - GEMM_BLOCKS;   // 0..255
        int wave = tid >> 6;
        int lane = tid & 63;
#pragma unroll
        for (int i = 0; i < 8; ++i) {
            int row = tb * 32 + wave * 8 + i;
            int lab = y_true[row];
            short8_t a8 = *(const short8_t*)(Abf + (size_t)row * DIM + lane * 8);
            float4 w0 = *(const float4*)(W + (size_t)lab * DIM + lane * 8);
            float4 w1 = *(const float4*)(W + (size_t)lab * DIM + lane * 8 + 4);
            float s = b2f(a8[0]) * w0.x + b2f(a8[1]) * w0.y
                    + b2f(a8[2]) * w0.z + b2f(a8[3]) * w0.w
                    + b2f(a8[4]) * w1.x + b2f(a8[5]) * w1.y
                    + b2f(a8[6]) * w1.z + b2f(a8[7]) * w1.w;
#pragma unroll
            for (int off = 32; off; off >>= 1) s += __shfl_xor(s, off);
            if (lane == 0) true_v[row] = s + b[lab] + neg_log_expected(lab);
        }
        __syncthreads();
    }

    // ---- completion counting; last block merges partials and writes mean ----
    __syncthreads();
    if (tid == 0) {
        __threadfence();                       // release: psum/true_v visible
        int old = atomicAdd(counter, 1);
        s_last = (old == TOTAL_BLOCKS - 1) ? 1 : 0;
    }
    __syncthreads();
    if (!s_last) return;

    __threadfence();                           // acquire
    float tot = 0.f;
#pragma unroll
    for (int i = 0; i < BATCH / 256; ++i) {
        int r = tid + i * 256;
        float4 ps = *(const float4*)(psum + (size_t)r * NCHUNK);
        float t = true_v[r];
        float s = ps.x + ps.y + ps.z + ps.w + expf(t - M0C);
        tot += logf(s) + M0C - t;
    }
    float* red = (float*)smem;
    red[tid] = tot;
    __syncthreads();
    for (int st = 128; st; st >>= 1) {
        if (tid < st) red[tid] += red[tid + st];
        __syncthreads();
    }
    if (tid == 0) out[0] = red[0] / (float)BATCH;
}

extern "C" void kernel_launch(void* const* d_in, const int* in_sizes, int n_in,
                              void* d_out, int out_size, void* d_ws, size_t ws_size,
                              hipStream_t stream) {
    const int*   y_true  = (const int*)d_in[0];
    const float* y_pred  = (const float*)d_in[1];
    const float* W       = (const float*)d_in[2];
    const float* b       = (const float*)d_in[3];
    const int*   sampled = (const int*)d_in[4];

    char* ws = (char*)d_ws;
    unsigned short* ypredB = (unsigned short*)ws;                 // 8 MB
    unsigned short* Wg     = (unsigned short*)(ws + 8388608);     // 1 MB
    float* adj    = (float*)(ws + 9437184);                       // 4 KB
    float* true_v = (float*)(ws + 9441280);                       // 32 KB
    float* psum   = (float*)(ws + 9474048);                       // 128 KB
    int*   counter = (int*)(ws + 9605120);                        // 4 B

    prep_kernel<<<2560, 256, 0, stream>>>(y_pred, W, b, sampled, Wg, adj,
                                          ypredB, counter);
    gemm_fused_kernel<<<TOTAL_BLOCKS, 256, 0, stream>>>(
        ypredB, Wg, sampled, adj, y_true, W, b, true_v, psum, counter,
        (float*)d_out);
}

// Round 6
// 41.487 us; speedup vs baseline: 1.3690x; 1.3690x over previous
//
#include <hip/hip_runtime.h>
#include <hip/hip_bf16.h>
#include <math.h>

#define S_SAMPLED 1000
#define SPAD      1024
#define DIM       512
#define BATCH     8192

#define BM 128
#define BN 256
#define BKT 64                 // K per tile (128 bytes)
#define KTILES (DIM / BKT)     // 8
#define NCHUNK 4               // SPAD / BN
#define GEMM_BLOCKS 256
#define M0C 20.0f              // fixed softmax max bound (logits <= ~8; HW-verified r5)

typedef __attribute__((ext_vector_type(8))) short short8_t;  // 8 bf16
typedef __attribute__((ext_vector_type(4))) float f32x4_t;

__device__ __forceinline__ float neg_log_expected(int c) {
    const float log_vp1 = 11.5129354649f;   // log(100001)
    float p = log1pf(1.0f / (float)(c + 1)) / log_vp1;
    float E = -expm1f((float)S_SAMPLED * log1pf(-p));
    return -logf(E);
}

__device__ __forceinline__ unsigned short f2bf(float x) {
    __hip_bfloat16 h = __float2bfloat16(x);
    union { __hip_bfloat16 h; unsigned short u; } cv; cv.h = h; return cv.u;
}

__device__ __forceinline__ void load_lds16(const void* g, void* l) {
    __builtin_amdgcn_global_load_lds(
        (const __attribute__((address_space(1))) void*)g,
        (__attribute__((address_space(3))) void*)l, 16, 0, 0);
}

// involution on byte addr: bits 4-6 ^= row&7 (rows are 128B apart)
__device__ __forceinline__ int swz(int lin) { return lin ^ (((lin >> 7) & 7) << 4); }

// ------------- kernel 0: fused prep (identical to round 4) ------------------
// blocks 0..511   : gather+cast W[sampled] -> Wg bf16, compute adj (2 rows/blk)
// blocks 512..2559: true logits (f32) + cast y_pred -> bf16 (4 rows/blk)
__global__ __launch_bounds__(256) void prep_kernel(
    const int* __restrict__ y_true, const float* __restrict__ y_pred,
    const float* __restrict__ W, const float* __restrict__ b,
    const int* __restrict__ sampled,
    unsigned short* __restrict__ Wg, float* __restrict__ adj,
    float* __restrict__ true_out, unsigned short* __restrict__ ypredB,
    int* __restrict__ counter)
{
    int bid = blockIdx.x;
    if (bid == 0 && threadIdx.x == 0) *counter = 0;
    if (bid < 512) {
        int row = bid * 2 + (threadIdx.x >> 7);   // 0..1023
        int t   = threadIdx.x & 127;              // 128 threads * 4 elems
        if (t == 0) {
            if (row < S_SAMPLED) {
                int c = sampled[row];
                adj[row] = b[c] + neg_log_expected(c);
            } else adj[row] = -1e30f;
        }
        unsigned short* dst = Wg + (size_t)row * DIM + t * 4;
        if (row < S_SAMPLED) {
            float4 f = *(const float4*)(W + (size_t)sampled[row] * DIM + t * 4);
            ushort4 o;
            o.x = f2bf(f.x); o.y = f2bf(f.y); o.z = f2bf(f.z); o.w = f2bf(f.w);
            *(ushort4*)dst = o;
        } else {
            *(ushort4*)dst = make_ushort4(0, 0, 0, 0);
        }
    } else {
        int row  = (bid - 512) * 4 + (threadIdx.x >> 6);
        int lane = threadIdx.x & 63;
        int lab  = y_true[row];
        const float4* ap = (const float4*)(y_pred + (size_t)row * DIM);
        const float4* wp = (const float4*)(W + (size_t)lab * DIM);
        float s = 0.f;
#pragma unroll
        for (int u = 0; u < 2; ++u) {
            float4 a = ap[lane + u * 64];
            float4 w = wp[lane + u * 64];
            s += a.x * w.x + a.y * w.y + a.z * w.z + a.w * w.w;
            ushort4 o;
            o.x = f2bf(a.x); o.y = f2bf(a.y); o.z = f2bf(a.z); o.w = f2bf(a.w);
            *(ushort4*)(ypredB + (size_t)row * DIM + (lane + u * 64) * 4) = o;
        }
#pragma unroll
        for (int off = 32; off; off >>= 1) s += __shfl_xor(s, off);
        if (lane == 0) true_out[row] = s + b[lab] + neg_log_expected(lab);
    }
}

// ------------- kernel 1: MFMA GEMM + fixed-max partial LSE + tail finalize --
// 1-D grid 256 blocks (XCD-swizzled), 512 threads = 8 waves (4 Mwaves x 2 Nwaves)
__global__ __launch_bounds__(512, 2) void gemm_partial_kernel(
    const unsigned short* __restrict__ Abf,   // y_pred bf16 [BATCH][DIM]
    const unsigned short* __restrict__ Wg,    // gathered W bf16 [SPAD][DIM]
    const int*   __restrict__ sampled,
    const float* __restrict__ adj,
    const int*   __restrict__ y_true,
    const float* __restrict__ true_v,         // [BATCH]
    float*       __restrict__ psum,           // [BATCH][NCHUNK]
    int*         __restrict__ counter,
    float*       __restrict__ out)
{
    __shared__ __align__(16) char smem[98304 + 2048];
    __shared__ int s_last;
    char* As0 = smem;
    char* As1 = smem + 16384;
    char* Bs0 = smem + 32768;
    char* Bs1 = smem + 65536;
    float* reds = (float*)(smem + 98304);          // [2][128]

    // XCD-aware remap: all 4 n-chunks of an m-stripe on one XCD
    int wg = blockIdx.x;
    int sw = (wg & 7) * 32 + (wg >> 3);     // bijective, 256 blocks
    const int m0    = (sw >> 2) * BM;
    const int chunk = sw & 3;
    const int n0    = chunk * BN;

    const int tid  = threadIdx.x;
    const int lane = tid & 63;
    const int wid  = tid >> 6;
    const int wr   = wid >> 1;
    const int wc   = wid & 1;
    const int g    = lane >> 4;
    const int lcol = lane & 15;

    const char* AB = (const char*)Abf;
    const char* WB = (const char*)Wg;

    // staging: linear LDS dest (tid*16), source pre-inverse-swizzled (rule #21)
    int a_src[2], b_src[4];
#pragma unroll
    for (int it = 0; it < 2; ++it) {
        int d = it * 8192 + tid * 16;
        int row = d >> 7;
        int kb  = (d & 127) ^ ((row & 7) << 4);
        a_src[it] = (m0 + row) * (DIM * 2) + kb;
    }
#pragma unroll
    for (int it = 0; it < 4; ++it) {
        int d = it * 8192 + tid * 16;
        int col = d >> 7;
        int kb  = (d & 127) ^ ((col & 7) << 4);
        b_src[it] = (n0 + col) * (DIM * 2) + kb;
    }

    int a_roff[2][2], b_roff[8][2];
#pragma unroll
    for (int mi = 0; mi < 2; ++mi)
#pragma unroll
        for (int ks = 0; ks < 2; ++ks)
            a_roff[mi][ks] = swz((wr * 32 + mi * 16 + lcol) * 128 + ks * 64 + g * 16);
#pragma unroll
    for (int nj = 0; nj < 8; ++nj)
#pragma unroll
        for (int ks = 0; ks < 2; ++ks)
            b_roff[nj][ks] = swz((wc * 128 + nj * 16 + lcol) * 128 + ks * 64 + g * 16);

    f32x4_t acc[2][8] = {};

#define STAGE(AsP, BsP, kt) do {                                     \
        int kb_ = (kt) * (BKT * 2);                                  \
        load_lds16(AB + a_src[0] + kb_, (AsP) + wid * 1024);         \
        load_lds16(AB + a_src[1] + kb_, (AsP) + 8192 + wid * 1024);  \
        load_lds16(WB + b_src[0] + kb_, (BsP) + wid * 1024);         \
        load_lds16(WB + b_src[1] + kb_, (BsP) + 8192 + wid * 1024);  \
        load_lds16(WB + b_src[2] + kb_, (BsP) + 16384 + wid * 1024); \
        load_lds16(WB + b_src[3] + kb_, (BsP) + 24576 + wid * 1024); \
    } while (0)

#define COMPUTE(AsP, BsP) do {                                                        \
        _Pragma("unroll")                                                             \
        for (int ks = 0; ks < 2; ++ks) {                                              \
            short8_t a0 = *(const short8_t*)((AsP) + a_roff[0][ks]);                  \
            short8_t a1 = *(const short8_t*)((AsP) + a_roff[1][ks]);                  \
            _Pragma("unroll")                                                         \
            for (int nj = 0; nj < 8; ++nj) {                                          \
                short8_t bv = *(const short8_t*)((BsP) + b_roff[nj][ks]);             \
                acc[0][nj] = __builtin_amdgcn_mfma_f32_16x16x32_bf16(a0, bv, acc[0][nj], 0, 0, 0); \
                acc[1][nj] = __builtin_amdgcn_mfma_f32_16x16x32_bf16(a1, bv, acc[1][nj], 0, 0, 0); \
            }                                                                         \
        }                                                                             \
    } while (0)

    // ---- K loop: counted-vmcnt double-buffer (T3/T4), raw barriers ----
    __builtin_amdgcn_sched_barrier(0);
    STAGE(As0, Bs0, 0);
    STAGE(As1, Bs1, 1);
#pragma unroll
    for (int t = 0; t < KTILES; ++t) {
        if (t < KTILES - 1) asm volatile("s_waitcnt vmcnt(6)" ::: "memory");
        else                asm volatile("s_waitcnt vmcnt(0)" ::: "memory");
        __builtin_amdgcn_s_barrier();
        __builtin_amdgcn_sched_barrier(0);
        const char* AsP = (t & 1) ? As1 : As0;
        const char* BsP = (t & 1) ? Bs1 : Bs0;
        __builtin_amdgcn_s_setprio(1);
        COMPUTE(AsP, BsP);
        __builtin_amdgcn_s_setprio(0);
        __builtin_amdgcn_sched_barrier(0);
        __builtin_amdgcn_s_barrier();
        if (t + 2 < KTILES) STAGE((t & 1) ? As1 : As0, (t & 1) ? Bs1 : Bs0, t + 2);
    }
    __builtin_amdgcn_sched_barrier(0);

    // ---- epilogue: adj + hit mask, fixed-max partial sum of exp(x - M0) ----
    // C layout: col = lane&15, row = (lane>>4)*4 + r
    int   labs[2][4];
    float srow[2][4];
#pragma unroll
    for (int mi = 0; mi < 2; ++mi)
#pragma unroll
        for (int r = 0; r < 4; ++r) {
            labs[mi][r] = y_true[m0 + wr * 32 + mi * 16 + g * 4 + r];
            srow[mi][r] = 0.f;
        }

    float ajv[8]; int scv[8];
#pragma unroll
    for (int nj = 0; nj < 8; ++nj) {
        int cg = n0 + wc * 128 + nj * 16 + lcol;
        ajv[nj] = adj[cg];
        scv[nj] = (cg < S_SAMPLED) ? sampled[cg] : -2147483647;
    }

#pragma unroll
    for (int mi = 0; mi < 2; ++mi)
#pragma unroll
        for (int nj = 0; nj < 8; ++nj) {
#pragma unroll
            for (int r = 0; r < 4; ++r) {
                float x = acc[mi][nj][r] + ajv[nj];
                if (scv[nj] == labs[mi][r]) x -= 1e9f;
                srow[mi][r] += expf(x - M0C);   // hit/pad -> exp(-huge) = 0
            }
        }

#pragma unroll
    for (int s = 1; s < 16; s <<= 1)
#pragma unroll
        for (int mi = 0; mi < 2; ++mi)
#pragma unroll
            for (int r = 0; r < 4; ++r)
                srow[mi][r] += __shfl_xor(srow[mi][r], s);
    if (lcol == 0) {
#pragma unroll
        for (int mi = 0; mi < 2; ++mi)
#pragma unroll
            for (int r = 0; r < 4; ++r)
                reds[wc * 128 + wr * 32 + mi * 16 + g * 4 + r] = srow[mi][r];
    }
    __syncthreads();

    if (tid < BM)
        psum[(size_t)(m0 + tid) * NCHUNK + chunk] = reds[tid] + reds[128 + tid];

    // ---- completion counting; last block merges partials and writes mean ----
    __syncthreads();
    if (tid == 0) {
        __threadfence();                       // release: psum visible
        int old = atomicAdd(counter, 1);
        s_last = (old == GEMM_BLOCKS - 1) ? 1 : 0;
    }
    __syncthreads();
    if (!s_last) return;

    __threadfence();                           // acquire
    float tot = 0.f;
#pragma unroll
    for (int i = 0; i < BATCH / 512; ++i) {
        int r = tid + i * 512;
        float4 ps = *(const float4*)(psum + (size_t)r * NCHUNK);
        float t = true_v[r];
        float s = ps.x + ps.y + ps.z + ps.w + expf(t - M0C);
        tot += logf(s) + M0C - t;
    }
    float* red = (float*)smem;
    red[tid] = tot;
    __syncthreads();
    for (int st = 256; st; st >>= 1) {
        if (tid < st) red[tid] += red[tid + st];
        __syncthreads();
    }
    if (tid == 0) out[0] = red[0] / (float)BATCH;
#undef STAGE
#undef COMPUTE
}

extern "C" void kernel_launch(void* const* d_in, const int* in_sizes, int n_in,
                              void* d_out, int out_size, void* d_ws, size_t ws_size,
                              hipStream_t stream) {
    const int*   y_true  = (const int*)d_in[0];
    const float* y_pred  = (const float*)d_in[1];
    const float* W       = (const float*)d_in[2];
    const float* b       = (const float*)d_in[3];
    const int*   sampled = (const int*)d_in[4];

    char* ws = (char*)d_ws;
    unsigned short* ypredB = (unsigned short*)ws;                 // 8 MB
    unsigned short* Wg     = (unsigned short*)(ws + 8388608);     // 1 MB
    float* adj     = (float*)(ws + 9437184);                      // 4 KB
    float* true_v  = (float*)(ws + 9441280);                      // 32 KB
    float* psum    = (float*)(ws + 9474048);                      // 128 KB
    int*   counter = (int*)(ws + 9605120);                        // 4 B

    prep_kernel<<<2560, 256, 0, stream>>>(y_true, y_pred, W, b, sampled,
                                          Wg, adj, true_v, ypredB, counter);
    gemm_partial_kernel<<<GEMM_BLOCKS, 512, 0, stream>>>(
        ypredB, Wg, sampled, adj, y_true, true_v, psum, counter, (float*)d_out);
}